// Round 4
// baseline (650.554 us; speedup 1.0000x reference)
//
#include <hip/hip_runtime.h>
#include <math.h>

// Problem constants (fixed by reference)
#define BATCH 2048
#define CH    32      // C
#define NN    144     // H*W = 12*12
#define KNN   9
#define PAD   36      // LDS row stride (floats): 16B-aligned, quad-rotation -> balanced banks
#define ACT   (2*NN)  // 288 active threads (2 batch elements per block)

// exact GELU: x * 0.5 * (1 + erf(x/sqrt(2)))  (jax.nn.gelu approximate=False)
__device__ __forceinline__ float gelu_exact(float x) {
    return 0.5f * x * (1.0f + erff(x * 0.70710678118654752440f));
}

// Two batch elements per workgroup. 320 threads (5 waves), 288 active in tail.
__global__ __launch_bounds__(320) void gcn_main(
        const float* __restrict__ xin,   // (B, C, H, W)
        const float* __restrict__ pos,   // (1, C, H, W)
        const float* __restrict__ rel,   // (1, N, N)
        const float* __restrict__ W1,  const float* __restrict__ B1,   // g_fc1 32x32
        const float* __restrict__ WC,  const float* __restrict__ BC,   // g_conv 64x64
        const float* __restrict__ W2,  const float* __restrict__ B2,   // g_fc2 32x64
        const float* __restrict__ F1,  const float* __restrict__ FB1,  // f_fc1 32x32
        const float* __restrict__ F2,  const float* __restrict__ FB2,  // f_fc2 32x32
        float* __restrict__ out) {
    const int t = threadIdx.x;
    const int g = (t >= NN) ? 1 : 0;         // batch slot within block
    const int n = t - g * NN;                // node index (valid when t < ACT)
    const long bb = (long)blockIdx.x * 2 + g;

    __shared__ __align__(16) float  s_xfT[2][NN * PAD];  // (n,c) g_fc1 output
    __shared__ float2 s_sr[2][NN];                       // (sq, rinv) per node

    const float* xb = xin + bb * (CH * NN) + n;   // column n of batch bb
    const float* pb = pos + n;

    float xf_n[CH];   // this thread's xf row (kept in regs through the tail)

    // ---- phase 1+2 fused: tmp col from global (coalesced), xf = W1@tmp + B1 ----
    if (t < ACT) {
        float tc[CH];
        #pragma unroll
        for (int c = 0; c < CH; ++c) tc[c] = xb[c * NN] + pb[c * NN];
        float sum = 0.f;
        #pragma unroll
        for (int o = 0; o < CH; ++o) {
            float acc = B1[o];
            #pragma unroll
            for (int c = 0; c < CH; ++c) acc += W1[o * CH + c] * tc[c];  // W1: s_load
            xf_n[o] = acc;
            sum += acc * acc;
        }
        // write own row to LDS (8x b128, rotation-balanced)
        float4* xr = (float4*)&s_xfT[g][n * PAD];
        #pragma unroll
        for (int q = 0; q < 8; ++q)
            xr[q] = make_float4(xf_n[4*q], xf_n[4*q+1], xf_n[4*q+2], xf_n[4*q+3]);
        float r = 1.0f / fmaxf(sqrtf(sum), 1e-12f);
        s_sr[g][n] = make_float2(sum * r * r, r);
    }
    __syncthreads();
    if (t >= ACT) return;    // tail is per-thread, read-only LDS: no more barriers

    // ---- phase 4: k-NN over distance rows ----
    const float rn  = s_sr[g][n].y;
    const float sqn = s_sr[g][n].x;
    float bestd[KNN];
    int   besti[KNN];
    #pragma unroll
    for (int k = 0; k < KNN; ++k) { bestd[k] = INFINITY; besti[k] = 0; }

    const float* reln = rel + n * NN;
    for (int mb = 0; mb < NN / 16; ++mb) {
        float rl[16];
        const float4* rp = (const float4*)(reln + mb * 16);
        #pragma unroll
        for (int q = 0; q < 4; ++q) {
            float4 v = rp[q];
            rl[4*q] = v.x; rl[4*q+1] = v.y; rl[4*q+2] = v.z; rl[4*q+3] = v.w;
        }
        #pragma unroll
        for (int mm = 0; mm < 16; ++mm) {
            const int m = mb * 16 + mm;
            const float4* row = (const float4*)&s_xfT[g][m * PAD];  // broadcast
            float dot = 0.f;
            #pragma unroll
            for (int q = 0; q < 8; ++q) {
                float4 v = row[q];
                dot += xf_n[4*q] * v.x + xf_n[4*q+1] * v.y
                     + xf_n[4*q+2] * v.z + xf_n[4*q+3] * v.w;
            }
            float2 sr = s_sr[g][m];
            float d = sqn - 2.0f * (dot * (rn * sr.y)) + sr.x + rl[mm];
            // strict < matches lax.top_k tie-break (lower index wins; m ascends)
            if (d < bestd[KNN - 1]) {
                bestd[KNN - 1] = d; besti[KNN - 1] = m;
                #pragma unroll
                for (int k = KNN - 1; k > 0; --k) {
                    if (bestd[k] < bestd[k - 1]) {
                        float td = bestd[k]; bestd[k] = bestd[k - 1]; bestd[k - 1] = td;
                        int   ti = besti[k]; besti[k] = besti[k - 1]; besti[k - 1] = ti;
                    }
                }
            }
        }
    }

    // ---- residual base: x2r = B2 + tmp (global re-read, L1-hot, coalesced) ----
    float x2r[CH];
    #pragma unroll
    for (int o = 0; o < CH; ++o) x2r[o] = B2[o] + xb[o * NN] + pb[o * NN];

    // ---- phase 5: max-relative (gathered) -> mrel ----
    float mrel[CH];
    #pragma unroll
    for (int c = 0; c < CH; ++c) mrel[c] = -INFINITY;
    #pragma unroll
    for (int k = 0; k < KNN; ++k) {
        const float4* nr = (const float4*)&s_xfT[g][besti[k] * PAD];
        #pragma unroll
        for (int q = 0; q < 8; ++q) {
            float4 v = nr[q];
            mrel[4*q]   = fmaxf(mrel[4*q],   v.x);
            mrel[4*q+1] = fmaxf(mrel[4*q+1], v.y);
            mrel[4*q+2] = fmaxf(mrel[4*q+2], v.z);
            mrel[4*q+3] = fmaxf(mrel[4*q+3], v.w);
        }
    }
    #pragma unroll
    for (int c = 0; c < CH; ++c) mrel[c] -= xf_n[c];

    // ---- phase 6: hc = gelu(WC@stacked + BC); x2r += W2@hc (streamed per j) ----
    // stacked[2c] = xf_n[c], stacked[2c+1] = mrel[c]
    #pragma unroll 2
    for (int j = 0; j < 2 * CH; ++j) {
        float acc = BC[j];
        const float* wr = WC + j * 2 * CH;   // wave-uniform -> scalar loads
        #pragma unroll
        for (int c = 0; c < CH; ++c)
            acc += wr[2*c] * xf_n[c] + wr[2*c + 1] * mrel[c];
        float h = gelu_exact(acc);
        #pragma unroll
        for (int o = 0; o < CH; ++o) x2r[o] += W2[o * 2 * CH + j] * h;
    }

    // ---- phase 7: FFN + residual + store ----
    float yv[CH];
    #pragma unroll
    for (int o = 0; o < CH; ++o) {
        float acc = FB1[o];
        #pragma unroll
        for (int c = 0; c < CH; ++c) acc += F1[o * CH + c] * x2r[c];
        yv[o] = gelu_exact(acc);
    }
    float* ob = out + bb * (CH * NN) + n;
    #pragma unroll
    for (int o = 0; o < CH; ++o) {
        float acc = FB2[o];
        #pragma unroll
        for (int c = 0; c < CH; ++c) acc += F2[o * CH + c] * yv[c];
        ob[o * NN] = acc + x2r[o];
    }
}

extern "C" void kernel_launch(void* const* d_in, const int* in_sizes, int n_in,
                              void* d_out, int out_size, void* d_ws, size_t ws_size,
                              hipStream_t stream) {
    const float* xin = (const float*)d_in[0];
    const float* pos = (const float*)d_in[1];
    const float* rel = (const float*)d_in[2];
    const float* w1  = (const float*)d_in[3];
    const float* b1  = (const float*)d_in[4];
    const float* wc  = (const float*)d_in[5];
    const float* bc  = (const float*)d_in[6];
    const float* w2  = (const float*)d_in[7];
    const float* b2  = (const float*)d_in[8];
    const float* f1  = (const float*)d_in[9];
    const float* fb1 = (const float*)d_in[10];
    const float* f2  = (const float*)d_in[11];
    const float* fb2 = (const float*)d_in[12];
    float* out = (float*)d_out;

    dim3 grid(BATCH / 2), blk(320);
    gcn_main<<<grid, blk, 0, stream>>>(xin, pos, rel,
                                       w1, b1, wc, bc, w2, b2,
                                       f1, fb1, f2, fb2, out);
}